// Round 2
// baseline (306.866 us; speedup 1.0000x reference)
//
#include <hip/hip_runtime.h>
#include <cstdint>
#include <cstddef>

// Problem constants
#define S_LEN  2048
#define NHEAD  16
#define HDIM   64
#define KD     1024   // D_IN == D_OUT
#define BSROWS 8192   // B * S

typedef __attribute__((ext_vector_type(4))) float          floatx4;
typedef __attribute__((ext_vector_type(8))) __bf16         bf16x8;
typedef __attribute__((ext_vector_type(8))) unsigned short ushort8v;
typedef __attribute__((ext_vector_type(4))) unsigned short ushort4v;
typedef __attribute__((ext_vector_type(4))) float          float4v;

// fp32 -> bf16 round-to-nearest-even on the bit pattern (inputs are finite)
__device__ __forceinline__ unsigned short f2bf(float f) {
  unsigned int u = __float_as_uint(f);
  u += 0x7fffu + ((u >> 16) & 1u);
  return (unsigned short)(u >> 16);
}

// fast exp2 (single v_exp_f32)
#if __has_builtin(__builtin_amdgcn_exp2f)
#define EXP2F(x) __builtin_amdgcn_exp2f(x)
#else
#define EXP2F(x) exp2f(x)
#endif

// pack two fp32 into packed bf16 (truncation; bias cancels in O/l)
__device__ __forceinline__ unsigned int pack2bf(float a, float b) {
#if __has_builtin(__builtin_amdgcn_perm)
  return __builtin_amdgcn_perm(__float_as_uint(b), __float_as_uint(a), 0x07060302);
#else
  return (__float_as_uint(a) >> 16) | (__float_as_uint(b) & 0xffff0000u);
#endif
}

// async global->LDS, 16B per lane; LDS dest is wave-uniform base + lane*16
__device__ __forceinline__ void async_cp16(const void* gsrc, void* ldst) {
  __builtin_amdgcn_global_load_lds(
      (__attribute__((address_space(1))) void*)gsrc,
      (__attribute__((address_space(3))) void*)ldst,
      16, 0, 0);
}

// ---------------------------------------------------------------------------
// Kernel 1: fp32 -> bf16 conversion of x, W_q|W_k|W_v (concat), W_o
// ---------------------------------------------------------------------------
#define XN4 2097152   // B*S*D_IN / 4
#define WN4 262144    // 1024*1024 / 4

__global__ __launch_bounds__(256) void cvt_kernel(
    const float* __restrict__ x,  const float* __restrict__ wq,
    const float* __restrict__ wk, const float* __restrict__ wv,
    const float* __restrict__ wo,
    unsigned short* __restrict__ xb, unsigned short* __restrict__ wqkvb,
    unsigned short* __restrict__ wob)
{
  const int i = blockIdx.x * 256 + threadIdx.x;
  const float* src; unsigned short* dst; int off;
  if (i < XN4) { src = x; dst = xb; off = i; }
  else {
    const int j = i - XN4;
    if (j < WN4)          { src = wq; dst = wqkvb;           off = j; }
    else if (j < 2*WN4)   { src = wk; dst = wqkvb + 4*WN4;   off = j - WN4; }
    else if (j < 3*WN4)   { src = wv; dst = wqkvb + 8*WN4;   off = j - 2*WN4; }
    else                  { src = wo; dst = wob;             off = j - 3*WN4; }
  }
  const float4v v = ((const float4v*)src)[off];
  ushort4v o;
  o.x = f2bf(v.x); o.y = f2bf(v.y); o.z = f2bf(v.z); o.w = f2bf(v.w);
  ((ushort4v*)dst)[off] = o;
}

// ---------------------------------------------------------------------------
// Kernel 2: fused QKV projection, NT bf16 GEMM [8192,1024] x [3072,1024]^T
// R12 (this round), on top of R7 sync structure (ONE fused vmcnt(0)+lgkm
// barrier per BK=32 iteration, distance-1 prefetch):
//  (a) B-operand DIRECT FROM GLOBAL into registers (distance-1 reg prefetch).
//      Weights are L2-resident (6 MB); staging them through LDS doubled LDS
//      write traffic and put B's ds_read on the MFMA critical path. LDS
//      traffic per CU per iter: 192 KB -> 96 KB. Sync structure unchanged:
//      the same vmcnt(0) drain covers the B register loads.
//  (b) Q/K epilogue operand swap: acc = mfma(B,A) puts the 4 acc regs along
//      n -> staging becomes 16x ds_write_b64 instead of 64x scalar b16.
//      V needs m-major acc for its vectorized transpose staging -> template
//      split: ISV=false handles Q/K (grid y=0..15), ISV=true handles V
//      (grid y=0..7, n0 offset +2048). Both stage C at stride 136 (16B-
//      aligned rows).
// ---------------------------------------------------------------------------
template<bool ISV>
__global__ __launch_bounds__(256) void gemm_qkv_t(
    const unsigned short* __restrict__ A,
    const unsigned short* __restrict__ Bw,
    unsigned short* __restrict__ Qo,
    unsigned short* __restrict__ Ko,
    unsigned short* __restrict__ Vto)
{
  __shared__ unsigned short smem[17408];   // A dbuf (2x4096) | epilogue 128x136
  const int tid  = threadIdx.x;
  const int wave = tid >> 6, lane = tid & 63;
  const int quad = lane >> 4, l15 = lane & 15;
  const int wr = wave >> 1, wc = wave & 1;
  const int m0 = blockIdx.x * 128;
  const int n0 = ((int)blockIdx.y + (ISV ? 16 : 0)) * 128;

  // A staging: XOR-swizzled global source, linear LDS dest (R7 layout)
  const int srow = lane >> 2;
  const int scol = ((lane & 3) ^ ((srow >> 1) & 3)) * 8;
  const unsigned short* gA = A + (size_t)(m0 + wave * 32 + srow) * KD + scol;

  // B fragments direct from global: row n0+wc*64+j*16+l15, k-col it*32+quad*8
  const unsigned short* gBf = Bw + (size_t)(n0 + wc * 64 + l15) * KD + quad * 8;

  const floatx4 fzero = {0.f, 0.f, 0.f, 0.f};
  floatx4 acc[4][4];
#pragma unroll
  for (int i = 0; i < 4; i++)
#pragma unroll
    for (int j = 0; j < 4; j++) acc[i][j] = fzero;

  // prologue: stage A tile 0 -> buf 0; load B frags for it=0
  {
    unsigned short* lA = smem + wave * 1024;
    async_cp16(gA,                   lA);
    async_cp16(gA + (size_t)16 * KD, lA + 512);
  }
  bf16x8 bcur[4], bnext[4];
#pragma unroll
  for (int j = 0; j < 4; j++)
    bcur[j] = *(const bf16x8*)&gBf[(size_t)j * 16 * KD];

  const int lsw = (l15 >> 1) & 3;

#pragma unroll 2
  for (int it = 0; it < 32; it++) {
    asm volatile("s_waitcnt vmcnt(0) lgkmcnt(0)\n\ts_barrier" ::: "memory");
    if (it + 1 < 32) {
      const int nb = (it + 1) & 1;
      const int ko = (it + 1) * 32;
      unsigned short* lA = smem + nb * 4096 + wave * 1024;
      async_cp16(gA + ko,                   lA);
      async_cp16(gA + ko + (size_t)16 * KD, lA + 512);
#pragma unroll
      for (int j = 0; j < 4; j++)
        bnext[j] = *(const bf16x8*)&gBf[(size_t)j * 16 * KD + ko];
    }
    const unsigned short* As = smem + (it & 1) * 4096;

    bf16x8 af[4];
#pragma unroll
    for (int i = 0; i < 4; i++)
      af[i] = *(const bf16x8*)&As[(wr * 64 + i * 16 + l15) * 32 + (quad ^ lsw) * 8];
#pragma unroll
    for (int i = 0; i < 4; i++)
#pragma unroll
      for (int j = 0; j < 4; j++) {
        if (ISV)
          acc[i][j] = __builtin_amdgcn_mfma_f32_16x16x32_bf16(af[i], bcur[j], acc[i][j], 0, 0, 0);
        else
          acc[i][j] = __builtin_amdgcn_mfma_f32_16x16x32_bf16(bcur[j], af[i], acc[i][j], 0, 0, 0);
      }
#pragma unroll
    for (int j = 0; j < 4; j++) bcur[j] = bnext[j];
  }

  const int h0 = (n0 & 1023) >> 6;                // first head of this n-block
  const int b = m0 >> 11, sl = m0 & 2047;

  if (!ISV) {
    // swapped acc: acc[i][j][r] = C[m=wr*64+i*16+l15][n=wc*64+j*16+quad*4+r]
    const int which = n0 >> 10;                   // 0:Q 1:K
    unsigned short* dst = which ? Ko : Qo;
    const float scale = which ? 1.0f : 0.18033688011112042f;  // Q: 0.125*log2(e)
    __syncthreads();                              // staging dead -> reuse as Ct[s][n] stride 136
    const int srw = wr * 64 + l15;
    const int scl = wc * 64 + quad * 4;
#pragma unroll
    for (int i = 0; i < 4; i++)
#pragma unroll
      for (int j = 0; j < 4; j++) {
        ushort4v t4;
#pragma unroll
        for (int r = 0; r < 4; r++) t4[r] = f2bf(acc[i][j][r] * scale);
        *(ushort4v*)&smem[(srw + i * 16) * 136 + scl + j * 16] = t4;
      }
    __syncthreads();
#pragma unroll
    for (int t = 0; t < 8; t++) {
      const int c   = t * 256 + tid;
      const int hd8 = (c & 7) * 8;
      const int hh  = (c >> 3) & 1;
      const int s   = c >> 4;
      const ushort8v val = *(const ushort8v*)&smem[s * 136 + hh * 64 + hd8];
      *(ushort8v*)&dst[((size_t)((b * NHEAD + h0 + hh) * S_LEN + sl + s)) * HDIM + hd8] = val;
    }
  } else {
    // V (unswapped acc): stage TRANSPOSED Ct[n][s] (stride 136), Vt stores.
    __syncthreads();
    const int crow = wr * 64 + quad * 4;          // s_local
    const int ccol = wc * 64 + l15;               // n_local
#pragma unroll
    for (int i = 0; i < 4; i++)
#pragma unroll
      for (int j = 0; j < 4; j++) {
        ushort4v t4;
#pragma unroll
        for (int r = 0; r < 4; r++) t4[r] = f2bf(acc[i][j][r]);
        *(ushort4v*)&smem[(ccol + j * 16) * 136 + crow + i * 16] = t4;
      }
    __syncthreads();
#pragma unroll
    for (int t = 0; t < 8; t++) {
      const int c  = t * 256 + tid;
      const int nl = c >> 4, sc = (c & 15) * 8;
      const ushort8v val = *(const ushort8v*)&smem[nl * 136 + sc];
      *(ushort8v*)&Vto[((size_t)((b * NHEAD + h0 + (nl >> 6)) * HDIM + (nl & 63))) * S_LEN + sl + sc] = val;
    }
  }
}

// ---------------------------------------------------------------------------
// Kernel 3: causal flash attention, S^T formulation, ASYNC-PIPELINED.
// (unchanged from R11 — verified passing: T5 setprio around both MFMA
// clusters; async double-buffered K/V; ONE fused vmcnt(0)+lgkm barrier per
// 64-key tile; P stride-68 b64 round-trip; no running max.)
// ---------------------------------------------------------------------------
__global__ __launch_bounds__(512, 6) void attn_kernel(
    const unsigned short* __restrict__ Qg_,
    const unsigned short* __restrict__ Kg_,
    const unsigned short* __restrict__ Vtg_,
    unsigned short* __restrict__ CTX)
{
  // shorts: buf0 K@0[4096] V@4096[4096] | buf1 K@8192 V@12288 | P@16384 8x[16*68]
  __shared__ unsigned short smem[25088];   // 50176 B
  const int tid  = threadIdx.x, wave = tid >> 6, lane = tid & 63;
  const int quad = lane >> 4, l15 = lane & 15;
  unsigned short* Pw = smem + 16384 + wave * 1088;   // [16][68] per wave

  const int bh = (int)blockIdx.x;
  const int yy = (int)blockIdx.y;
  // qt perm: {0,1,2,3, 7,6,5,4, 8,9,10,11, 15,14,13,12} — columns sum to 30
  const int qt = (yy < 4) ? yy : (yy < 8) ? (11 - yy) : (yy < 12) ? yy : (27 - yy);
  const int q0 = qt * 128;
  const size_t base = (size_t)bh * (S_LEN * HDIM);
  const unsigned short* Qg  = Qg_  + base;
  const unsigned short* Kg  = Kg_  + base;
  const unsigned short* Vtg = Vtg_ + base;        // [hd][s]
  const int qw = q0 + wave * 16;                  // wave's 16 q-rows

  const int strow = lane >> 3;
  const int stxc  = (lane & 7) ^ strow;
  const unsigned short* kstage = Kg  + (size_t)(wave * 8 + strow) * HDIM  + stxc * 8;
  const unsigned short* vstage = Vtg + (size_t)(wave * 8 + strow) * S_LEN + stxc * 8;
  unsigned short* kd0 = smem + wave * 512;
  unsigned short* vd0 = smem + 4096 + wave * 512;

  // prologue: async stage tile 0 -> buf 0
  async_cp16(kstage, kd0);
  async_cp16(vstage, vd0);

  // Q fragments direct from global (one-time; B-operand B[n=q][k=dim])
  bf16x8 qf[2];
#pragma unroll
  for (int ks = 0; ks < 2; ks++)
    qf[ks] = *(const bf16x8*)&Qg[(size_t)(qw + l15) * HDIM + ks * 32 + quad * 8];

  const int sw0 = ((quad)     ^ (l15 & 7)) * 8;   // K/V frag swizzled col offs
  const int sw1 = ((4 + quad) ^ (l15 & 7)) * 8;

  const floatx4 fzero = {0.f, 0.f, 0.f, 0.f};
  floatx4 O[4];
  float l_part = 0.f;
#pragma unroll
  for (int mt = 0; mt < 4; mt++) O[mt] = fzero;

  const int ntiles = 2 * qt + 2;   // covers keys 0..q0+127 >= qw+15

  for (int j = 0; j < ntiles; j++) {
    asm volatile("s_waitcnt vmcnt(0) lgkmcnt(0)\n\ts_barrier" ::: "memory");
    if (j + 1 < ntiles) {
      const int nb = (j + 1) & 1;
      async_cp16(kstage + (size_t)(j + 1) * 64 * HDIM, kd0 + nb * 8192);
      async_cp16(vstage + (size_t)(j + 1) * 64,        vd0 + nb * 8192);
    }
    const int k0 = j * 64;
    if (k0 > qw + 15) continue;                 // above diagonal for this wave
    const unsigned short* Ksb = smem + (j & 1) * 8192;
    const unsigned short* Vsb = Ksb + 4096;
    const int krel = qw + 15 - k0;              // max key offset needed

    // S^T = K Q^T  (A = K frag just-in-time, B = Q reg frag)
    floatx4 sa[4];
#pragma unroll
    for (int kt = 0; kt < 4; kt++) sa[kt] = fzero;
    __builtin_amdgcn_s_setprio(1);              // T5: favor MFMA wave (m191)
#pragma unroll
    for (int kt = 0; kt < 4; kt++) {
      if (kt * 16 <= krel) {
        const unsigned short* kr = &Ksb[(kt * 16 + l15) * 64];
        sa[kt] = __builtin_amdgcn_mfma_f32_16x16x32_bf16(*(const bf16x8*)(kr + sw0), qf[0], sa[kt], 0, 0, 0);
        sa[kt] = __builtin_amdgcn_mfma_f32_16x16x32_bf16(*(const bf16x8*)(kr + sw1), qf[1], sa[kt], 0, 0, 0);
      }
    }
    __builtin_amdgcn_s_setprio(0);

    const int qrow = qw + l15;                  // this lane's q (S^T col)
#pragma unroll
    for (int kt = 0; kt < 4; kt++) {
      const int kbase = k0 + kt * 16;
      unsigned short* pdst = &Pw[l15 * 68 + kt * 16 + quad * 4];
      if (kt * 16 <= krel) {
        if (kbase + 15 > qw) {                  // boundary subtile: mask
#pragma unroll
          for (int r = 0; r < 4; r++)
            if (kbase + quad * 4 + r > qrow) sa[kt][r] = -INFINITY;
        }
        const float p0 = EXP2F(sa[kt][0]), p1 = EXP2F(sa[kt][1]);
        const float p2 = EXP2F(sa[kt][2]), p3 = EXP2F(sa[kt][3]);
        l_part += (p0 + p1) + (p2 + p3);
        uint2 pk; pk.x = pack2bf(p0, p1); pk.y = pack2bf(p2, p3);
        *(uint2*)pdst = pk;
      } else if ((kt >> 1) * 32 <= krel) {      // zero-fill rest of read half
        uint2 z; z.x = 0u; z.y = 0u;
        *(uint2*)pdst = z;
      }
    }
    asm volatile("s_waitcnt lgkmcnt(0)" ::: "memory");  // P writes (wave-local)

    // O^T += V^T P^T : A = Vt frag (swizzled LDS), B = P frag (b64 reads)
#pragma unroll
    for (int ks = 0; ks < 2; ks++) {
      if (ks * 32 > krel) break;
      const unsigned short* ps = &Pw[l15 * 68 + ks * 32 + quad * 8];
      union { ushort4v h[2]; bf16x8 v; } pu;
      pu.h[0] = *(const ushort4v*)ps;
      pu.h[1] = *(const ushort4v*)(ps + 4);
      __builtin_amdgcn_s_setprio(1);            // T5: favor MFMA wave (m191)
#pragma unroll
      for (int mt = 0; mt < 4; mt++) {
        const bf16x8 vf = *(const bf16x8*)(&Vsb[(mt * 16 + l15) * 64] + (ks ? sw1 : sw0));
        O[mt] = __builtin_amdgcn_mfma_f32_16x16x32_bf16(vf, pu.v, O[mt], 0, 0, 0);
      }
      __builtin_amdgcn_s_setprio(0);
    }
  }

  // l: reduce partial sums across the 4 quads (keys were split across quads)
#pragma unroll
  for (int d = 16; d < 64; d <<= 1)
    l_part += __shfl_xor(l_part, d, 64);

  // epilogue: O^T (hd=row, q=col) -> Pw [q][hd] stride 68 -> coalesced CTX
  {
    const float inv = 1.0f / l_part;
#pragma unroll
    for (int mt = 0; mt < 4; mt++)
#pragma unroll
      for (int a = 0; a < 2; a++) {
        const unsigned int pk =
            (unsigned int)f2bf(O[mt][2 * a] * inv) |
            ((unsigned int)f2bf(O[mt][2 * a + 1] * inv) << 16);
        *(unsigned int*)&Pw[l15 * 68 + mt * 16 + quad * 4 + 2 * a] = pk;
      }
  }
  asm volatile("s_waitcnt lgkmcnt(0)" ::: "memory");
  const int b = bh >> 4, h = bh & 15;
#pragma unroll
  for (int it = 0; it < 2; it++) {
    const int g = it * 64 + lane;
    const int row = g >> 3, c8 = (g & 7) * 8;
    union { ushort4v h[2]; ushort8v v; } ou;
    ou.h[0] = *(const ushort4v*)&Pw[row * 68 + c8];
    ou.h[1] = *(const ushort4v*)&Pw[row * 68 + c8 + 4];
    const int s = qw + row;
    *(ushort8v*)&CTX[((size_t)(b * S_LEN + s)) * KD + h * HDIM + c8] = ou.v;
  }
}

// ---------------------------------------------------------------------------
// Kernel 4: output projection ctx[8192,1024] x W_o[1024,1024]^T + b_o -> fp32
// R12: B (W_o, 2 MB, L2-resident) direct-from-global reg prefetch; A-only LDS
// staging; epilogue operand swap -> coalesced float4 stores + float4 bias.
// ---------------------------------------------------------------------------
__global__ __launch_bounds__(256) void gemm_out(
    const unsigned short* __restrict__ A,
    const unsigned short* __restrict__ Bw,
    const float* __restrict__ bias,
    float* __restrict__ out)
{
  __shared__ unsigned short smem[8192];   // A dbuf only (2 x 4096)
  const int tid  = threadIdx.x;
  const int wave = tid >> 6, lane = tid & 63;
  const int quad = lane >> 4, l15 = lane & 15;
  const int wr = wave >> 1, wc = wave & 1;
  const int m0 = blockIdx.x * 128, n0 = blockIdx.y * 128;

  const int srow = lane >> 2;
  const int scol = ((lane & 3) ^ ((srow >> 1) & 3)) * 8;
  const unsigned short* gA = A + (size_t)(m0 + wave * 32 + srow) * KD + scol;
  const unsigned short* gBf = Bw + (size_t)(n0 + wc * 64 + l15) * KD + quad * 8;

  const floatx4 fzero = {0.f, 0.f, 0.f, 0.f};
  floatx4 acc[4][4];
#pragma unroll
  for (int i = 0; i < 4; i++)
#pragma unroll
    for (int j = 0; j < 4; j++) acc[i][j] = fzero;

  {
    unsigned short* lA = smem + wave * 1024;
    async_cp16(gA,                   lA);
    async_cp16(gA + (size_t)16 * KD, lA + 512);
  }
  bf16x8 bcur[4], bnext[4];
#pragma unroll
  for (int j = 0; j < 4; j++)
    bcur[j] = *(const bf16x8*)&gBf[(size_t)j * 16 * KD];

  const int lsw = (l15 >> 1) & 3;

#pragma unroll 2
  for (int it = 0; it < 32; it++) {
    asm volatile("s_waitcnt vmcnt(0) lgkmcnt(0)\n\ts_barrier" ::: "memory");
    if (it + 1 < 32) {
      const int nb = (it + 1) & 1;
      const int ko = (it + 1) * 32;
      unsigned short* lA = smem + nb * 4096 + wave * 1024;
      async_cp16(gA + ko,                   lA);
      async_cp16(gA + ko + (size_t)16 * KD, lA + 512);
#pragma unroll
      for (int j = 0; j < 4; j++)
        bnext[j] = *(const bf16x8*)&gBf[(size_t)j * 16 * KD + ko];
    }
    const unsigned short* As = smem + (it & 1) * 4096;

    bf16x8 af[4];
#pragma unroll
    for (int i = 0; i < 4; i++)
      af[i] = *(const bf16x8*)&As[(wr * 64 + i * 16 + l15) * 32 + (quad ^ lsw) * 8];
#pragma unroll
    for (int i = 0; i < 4; i++)
#pragma unroll
      for (int j = 0; j < 4; j++)
        acc[i][j] = __builtin_amdgcn_mfma_f32_16x16x32_bf16(bcur[j], af[i], acc[i][j], 0, 0, 0);
#pragma unroll
    for (int j = 0; j < 4; j++) bcur[j] = bnext[j];
  }

  // swapped acc: acc[i][j][r] = C[m=m0+wr*64+i*16+l15][n=n0+wc*64+j*16+quad*4+r]
#pragma unroll
  for (int j = 0; j < 4; j++) {
    const int nb4 = n0 + wc * 64 + j * 16 + quad * 4;
    const float4v bb = *(const float4v*)&bias[nb4];
#pragma unroll
    for (int i = 0; i < 4; i++) {
      const int m = m0 + wr * 64 + i * 16 + l15;
      float4v st;
#pragma unroll
      for (int r = 0; r < 4; r++) st[r] = acc[i][j][r] + bb[r];
      *(float4v*)&out[(size_t)m * KD + nb4] = st;
    }
  }
}

// ---------------------------------------------------------------------------
extern "C" void kernel_launch(void* const* d_in, const int* in_sizes, int n_in,
                              void* d_out, int out_size, void* d_ws, size_t ws_size,
                              hipStream_t stream) {
  (void)in_sizes; (void)n_in; (void)out_size;
  const float* x  = (const float*)d_in[0];
  const float* wq = (const float*)d_in[1];
  const float* wk = (const float*)d_in[2];
  const float* wv = (const float*)d_in[3];
  const float* wo = (const float*)d_in[4];
  const float* bo = (const float*)d_in[5];
  float* out = (float*)d_out;

  if (ws_size < (size_t)92274688) return;
  char* ws = (char*)d_ws;
  unsigned short* xb    = (unsigned short*)(ws);
  unsigned short* wqkvb = (unsigned short*)(ws + (size_t)16777216);
  unsigned short* wob   = (unsigned short*)(ws + (size_t)23068672);
  unsigned short* qws   = (unsigned short*)(ws + (size_t)25165824);
  unsigned short* kws   = (unsigned short*)(ws + (size_t)41943040);
  unsigned short* vtws  = (unsigned short*)(ws + (size_t)58720256);
  unsigned short* ctxws = (unsigned short*)(ws + (size_t)75497472);

  cvt_kernel<<<12288, 256, 0, stream>>>(x, wq, wk, wv, wo, xb, wqkvb, wob);
  gemm_qkv_t<false><<<dim3(64, 16), 256, 0, stream>>>(xb, wqkvb, qws, kws, vtws);
  gemm_qkv_t<true ><<<dim3(64,  8), 256, 0, stream>>>(xb, wqkvb, qws, kws, vtws);
  attn_kernel<<<dim3(64, 16), 512, 0, stream>>>(qws, kws, vtws, ctxws);
  gemm_out<<<dim3(64, 8), 256, 0, stream>>>(ctxws, wob, bo, out);
}

// Round 4
// 242.481 us; speedup vs baseline: 1.2655x; 1.2655x over previous
//
#include <hip/hip_runtime.h>
#include <cstdint>
#include <cstddef>

// Problem constants
#define S_LEN  2048
#define NHEAD  16
#define HDIM   64
#define KD     1024   // D_IN == D_OUT
#define BSROWS 8192   // B * S

typedef __attribute__((ext_vector_type(4))) float          floatx4;
typedef __attribute__((ext_vector_type(8))) __bf16         bf16x8;
typedef __attribute__((ext_vector_type(8))) unsigned short ushort8v;
typedef __attribute__((ext_vector_type(4))) unsigned short ushort4v;
typedef __attribute__((ext_vector_type(4))) float          float4v;

// fp32 -> bf16 round-to-nearest-even on the bit pattern (inputs are finite)
__device__ __forceinline__ unsigned short f2bf(float f) {
  unsigned int u = __float_as_uint(f);
  u += 0x7fffu + ((u >> 16) & 1u);
  return (unsigned short)(u >> 16);
}

// fast exp2 (single v_exp_f32)
#if __has_builtin(__builtin_amdgcn_exp2f)
#define EXP2F(x) __builtin_amdgcn_exp2f(x)
#else
#define EXP2F(x) exp2f(x)
#endif

// pack two fp32 into packed bf16 (truncation; bias cancels in O/l)
__device__ __forceinline__ unsigned int pack2bf(float a, float b) {
#if __has_builtin(__builtin_amdgcn_perm)
  return __builtin_amdgcn_perm(__float_as_uint(b), __float_as_uint(a), 0x07060302);
#else
  return (__float_as_uint(a) >> 16) | (__float_as_uint(b) & 0xffff0000u);
#endif
}

// async global->LDS, 16B per lane; LDS dest is wave-uniform base + lane*16
__device__ __forceinline__ void async_cp16(const void* gsrc, void* ldst) {
  __builtin_amdgcn_global_load_lds(
      (__attribute__((address_space(1))) void*)gsrc,
      (__attribute__((address_space(3))) void*)ldst,
      16, 0, 0);
}

// ---------------------------------------------------------------------------
// Kernel 1: fp32 -> bf16 conversion of x, W_q|W_k|W_v (concat), W_o
// ---------------------------------------------------------------------------
#define XN4 2097152   // B*S*D_IN / 4
#define WN4 262144    // 1024*1024 / 4

__global__ __launch_bounds__(256) void cvt_kernel(
    const float* __restrict__ x,  const float* __restrict__ wq,
    const float* __restrict__ wk, const float* __restrict__ wv,
    const float* __restrict__ wo,
    unsigned short* __restrict__ xb, unsigned short* __restrict__ wqkvb,
    unsigned short* __restrict__ wob)
{
  const int i = blockIdx.x * 256 + threadIdx.x;
  const float* src; unsigned short* dst; int off;
  if (i < XN4) { src = x; dst = xb; off = i; }
  else {
    const int j = i - XN4;
    if (j < WN4)          { src = wq; dst = wqkvb;           off = j; }
    else if (j < 2*WN4)   { src = wk; dst = wqkvb + 4*WN4;   off = j - WN4; }
    else if (j < 3*WN4)   { src = wv; dst = wqkvb + 8*WN4;   off = j - 2*WN4; }
    else                  { src = wo; dst = wob;             off = j - 3*WN4; }
  }
  const float4v v = ((const float4v*)src)[off];
  ushort4v o;
  o.x = f2bf(v.x); o.y = f2bf(v.y); o.z = f2bf(v.z); o.w = f2bf(v.w);
  ((ushort4v*)dst)[off] = o;
}

// ---------------------------------------------------------------------------
// Shared 128x128 K-loop (R11-verified structure): BOTH operands staged via
// async global_load_lds (16B, XOR-swizzled source, linear LDS dest), double
// buffered, ONE fused vmcnt(0)+lgkm barrier per BK=32 iteration, distance-1
// prefetch. R13: SWAP selects mfma(bfrag, af) so acc's 4 regs run along n
// (validated in R12: enables vectorized b64 epilogue staging for Q/K and
// coalesced float4 stores for gemm_out). R12's B-direct-from-global is
// REVERTED: per-lane scattered 64B loads (stride 2KB) behind the vmcnt(0)
// drain halved MfmaUtil (28->14%). Staging both operands is load-bearing.
// ---------------------------------------------------------------------------
template<bool SWAP>
__device__ __forceinline__ void kloop128(
    const unsigned short* __restrict__ gA,
    const unsigned short* __restrict__ gB,
    unsigned short* smem, floatx4 (&acc)[4][4],
    const int wave, const int quad, const int l15,
    const int wr, const int wc)
{
  {
    unsigned short* lA = smem + wave * 1024;
    unsigned short* lB = smem + 4096 + wave * 1024;
    async_cp16(gA,                    lA);
    async_cp16(gA + (size_t)16 * KD,  lA + 512);
    async_cp16(gB,                    lB);
    async_cp16(gB + (size_t)16 * KD,  lB + 512);
  }
  const int lsw = (l15 >> 1) & 3;

#pragma unroll 2
  for (int it = 0; it < 32; it++) {
    asm volatile("s_waitcnt vmcnt(0) lgkmcnt(0)\n\ts_barrier" ::: "memory");
    if (it + 1 < 32) {
      const int nb = (it + 1) & 1;
      const int ko = (it + 1) * 32;
      unsigned short* lA = smem + nb * 8192 + wave * 1024;
      unsigned short* lB = smem + nb * 8192 + 4096 + wave * 1024;
      async_cp16(gA + ko,                   lA);
      async_cp16(gA + ko + (size_t)16 * KD, lA + 512);
      async_cp16(gB + ko,                   lB);
      async_cp16(gB + ko + (size_t)16 * KD, lB + 512);
    }
    const unsigned short* As = smem + (it & 1) * 8192;
    const unsigned short* Bs = As + 4096;

    bf16x8 af[4], bfrag[4];
#pragma unroll
    for (int i = 0; i < 4; i++)
      af[i] = *(const bf16x8*)&As[(wr * 64 + i * 16 + l15) * 32 + (quad ^ lsw) * 8];
#pragma unroll
    for (int j = 0; j < 4; j++)
      bfrag[j] = *(const bf16x8*)&Bs[(wc * 64 + j * 16 + l15) * 32 + (quad ^ lsw) * 8];
#pragma unroll
    for (int i = 0; i < 4; i++)
#pragma unroll
      for (int j = 0; j < 4; j++) {
        if (SWAP)
          acc[i][j] = __builtin_amdgcn_mfma_f32_16x16x32_bf16(bfrag[j], af[i], acc[i][j], 0, 0, 0);
        else
          acc[i][j] = __builtin_amdgcn_mfma_f32_16x16x32_bf16(af[i], bfrag[j], acc[i][j], 0, 0, 0);
      }
  }
}

// ---------------------------------------------------------------------------
// Kernel 2: fused QKV projection, NT bf16 GEMM [8192,1024] x [3072,1024]^T
// Single dispatch (grid 64x24). Q/K blocks use SWAP=true K-loop (n-major acc
// -> b64 staging writes, validated R12); V uses SWAP=false + transposed
// staging (R11-verified).
// ---------------------------------------------------------------------------
__global__ __launch_bounds__(256) void gemm_qkv(
    const unsigned short* __restrict__ A,
    const unsigned short* __restrict__ Bw,
    unsigned short* __restrict__ Qo,
    unsigned short* __restrict__ Ko,
    unsigned short* __restrict__ Vto)
{
  __shared__ unsigned short smem[17408];
  const int tid  = threadIdx.x;
  const int wave = tid >> 6, lane = tid & 63;
  const int quad = lane >> 4, l15 = lane & 15;
  const int wr = wave >> 1, wc = wave & 1;
  const int m0 = blockIdx.x * 128, n0 = blockIdx.y * 128;

  const int srow = lane >> 2;
  const int scol = ((lane & 3) ^ ((srow >> 1) & 3)) * 8;   // XOR-swizzled source
  const unsigned short* gA = A  + (size_t)(m0 + wave * 32 + srow) * KD + scol;
  const unsigned short* gB = Bw + (size_t)(n0 + wave * 32 + srow) * KD + scol;

  const floatx4 fzero = {0.f, 0.f, 0.f, 0.f};
  floatx4 acc[4][4];
#pragma unroll
  for (int i = 0; i < 4; i++)
#pragma unroll
    for (int j = 0; j < 4; j++) acc[i][j] = fzero;

  const int which = n0 >> 10;                     // 0:Q 1:K 2:V
  const int h0 = (n0 & 1023) >> 6;                // first head of this n-block
  const int b = m0 >> 11, sl = m0 & 2047;

  if (which < 2) {
    kloop128<true>(gA, gB, smem, acc, wave, quad, l15, wr, wc);
    // swapped acc: acc[i][j][r] = C[m=wr*64+i*16+l15][n=wc*64+j*16+quad*4+r]
    unsigned short* dst = which ? Ko : Qo;
    const float scale = which ? 1.0f : 0.18033688011112042f;  // Q: 0.125*log2(e)
    __syncthreads();                              // staging dead -> reuse as Ct[s][n] stride 136
    const int srw = wr * 64 + l15;
    const int scl = wc * 64 + quad * 4;
#pragma unroll
    for (int i = 0; i < 4; i++)
#pragma unroll
      for (int j = 0; j < 4; j++) {
        ushort4v t4;
#pragma unroll
        for (int r = 0; r < 4; r++) t4[r] = f2bf(acc[i][j][r] * scale);
        *(ushort4v*)&smem[(srw + i * 16) * 136 + scl + j * 16] = t4;
      }
    __syncthreads();
#pragma unroll
    for (int t = 0; t < 8; t++) {
      const int c   = t * 256 + tid;
      const int hd8 = (c & 7) * 8;
      const int hh  = (c >> 3) & 1;
      const int s   = c >> 4;
      const ushort8v val = *(const ushort8v*)&smem[s * 136 + hh * 64 + hd8];
      *(ushort8v*)&dst[((size_t)((b * NHEAD + h0 + hh) * S_LEN + sl + s)) * HDIM + hd8] = val;
    }
  } else {
    kloop128<false>(gA, gB, smem, acc, wave, quad, l15, wr, wc);
    // V (m-major acc): stage TRANSPOSED Ct[n][s] (stride 136), Vt stores.
    __syncthreads();
    const int crow = wr * 64 + quad * 4;          // s_local
    const int ccol = wc * 64 + l15;               // n_local
#pragma unroll
    for (int i = 0; i < 4; i++)
#pragma unroll
      for (int j = 0; j < 4; j++) {
        ushort4v t4;
#pragma unroll
        for (int r = 0; r < 4; r++) t4[r] = f2bf(acc[i][j][r]);
        *(ushort4v*)&smem[(ccol + j * 16) * 136 + crow + i * 16] = t4;
      }
    __syncthreads();
#pragma unroll
    for (int t = 0; t < 8; t++) {
      const int c  = t * 256 + tid;
      const int nl = c >> 4, sc = (c & 15) * 8;
      const ushort8v val = *(const ushort8v*)&smem[nl * 136 + sc];
      *(ushort8v*)&Vto[((size_t)((b * NHEAD + h0 + (nl >> 6)) * HDIM + (nl & 63))) * S_LEN + sl + sc] = val;
    }
  }
}

// ---------------------------------------------------------------------------
// Kernel 3: causal flash attention, S^T formulation, ASYNC-PIPELINED.
// (unchanged from R11 — verified 239.2 µs run: T5 setprio around both MFMA
// clusters; async double-buffered K/V; ONE fused vmcnt(0)+lgkm barrier per
// 64-key tile; P stride-68 b64 round-trip; no running max.)
// ---------------------------------------------------------------------------
__global__ __launch_bounds__(512, 6) void attn_kernel(
    const unsigned short* __restrict__ Qg_,
    const unsigned short* __restrict__ Kg_,
    const unsigned short* __restrict__ Vtg_,
    unsigned short* __restrict__ CTX)
{
  // shorts: buf0 K@0[4096] V@4096[4096] | buf1 K@8192 V@12288 | P@16384 8x[16*68]
  __shared__ unsigned short smem[25088];   // 50176 B
  const int tid  = threadIdx.x, wave = tid >> 6, lane = tid & 63;
  const int quad = lane >> 4, l15 = lane & 15;
  unsigned short* Pw = smem + 16384 + wave * 1088;   // [16][68] per wave

  const int bh = (int)blockIdx.x;
  const int yy = (int)blockIdx.y;
  // qt perm: {0,1,2,3, 7,6,5,4, 8,9,10,11, 15,14,13,12} — columns sum to 30
  const int qt = (yy < 4) ? yy : (yy < 8) ? (11 - yy) : (yy < 12) ? yy : (27 - yy);
  const int q0 = qt * 128;
  const size_t base = (size_t)bh * (S_LEN * HDIM);
  const unsigned short* Qg  = Qg_  + base;
  const unsigned short* Kg  = Kg_  + base;
  const unsigned short* Vtg = Vtg_ + base;        // [hd][s]
  const int qw = q0 + wave * 16;                  // wave's 16 q-rows

  const int strow = lane >> 3;
  const int stxc  = (lane & 7) ^ strow;
  const unsigned short* kstage = Kg  + (size_t)(wave * 8 + strow) * HDIM  + stxc * 8;
  const unsigned short* vstage = Vtg + (size_t)(wave * 8 + strow) * S_LEN + stxc * 8;
  unsigned short* kd0 = smem + wave * 512;
  unsigned short* vd0 = smem + 4096 + wave * 512;

  // prologue: async stage tile 0 -> buf 0
  async_cp16(kstage, kd0);
  async_cp16(vstage, vd0);

  // Q fragments direct from global (one-time; B-operand B[n=q][k=dim])
  bf16x8 qf[2];
#pragma unroll
  for (int ks = 0; ks < 2; ks++)
    qf[ks] = *(const bf16x8*)&Qg[(size_t)(qw + l15) * HDIM + ks * 32 + quad * 8];

  const int sw0 = ((quad)     ^ (l15 & 7)) * 8;   // K/V frag swizzled col offs
  const int sw1 = ((4 + quad) ^ (l15 & 7)) * 8;

  const floatx4 fzero = {0.f, 0.f, 0.f, 0.f};
  floatx4 O[4];
  float l_part = 0.f;
#pragma unroll
  for (int mt = 0; mt < 4; mt++) O[mt] = fzero;

  const int ntiles = 2 * qt + 2;   // covers keys 0..q0+127 >= qw+15

  for (int j = 0; j < ntiles; j++) {
    asm volatile("s_waitcnt vmcnt(0) lgkmcnt(0)\n\ts_barrier" ::: "memory");
    if (j + 1 < ntiles) {
      const int nb = (j + 1) & 1;
      async_cp16(kstage + (size_t)(j + 1) * 64 * HDIM, kd0 + nb * 8192);
      async_cp16(vstage + (size_t)(j + 1) * 64,        vd0 + nb * 8192);
    }
    const int k0 = j * 64;
    if (k0 > qw + 15) continue;                 // above diagonal for this wave
    const unsigned short* Ksb = smem + (j & 1) * 8192;
    const unsigned short* Vsb = Ksb + 4096;
    const int krel = qw + 15 - k0;              // max key offset needed

    // S^T = K Q^T  (A = K frag just-in-time, B = Q reg frag)
    floatx4 sa[4];
#pragma unroll
    for (int kt = 0; kt < 4; kt++) sa[kt] = fzero;
    __builtin_amdgcn_s_setprio(1);              // T5: favor MFMA wave (m191)
#pragma unroll
    for (int kt = 0; kt < 4; kt++) {
      if (kt * 16 <= krel) {
        const unsigned short* kr = &Ksb[(kt * 16 + l15) * 64];
        sa[kt] = __builtin_amdgcn_mfma_f32_16x16x32_bf16(*(const bf16x8*)(kr + sw0), qf[0], sa[kt], 0, 0, 0);
        sa[kt] = __builtin_amdgcn_mfma_f32_16x16x32_bf16(*(const bf16x8*)(kr + sw1), qf[1], sa[kt], 0, 0, 0);
      }
    }
    __builtin_amdgcn_s_setprio(0);

    const int qrow = qw + l15;                  // this lane's q (S^T col)
#pragma unroll
    for (int kt = 0; kt < 4; kt++) {
      const int kbase = k0 + kt * 16;
      unsigned short* pdst = &Pw[l15 * 68 + kt * 16 + quad * 4];
      if (kt * 16 <= krel) {
        if (kbase + 15 > qw) {                  // boundary subtile: mask
#pragma unroll
          for (int r = 0; r < 4; r++)
            if (kbase + quad * 4 + r > qrow) sa[kt][r] = -INFINITY;
        }
        const float p0 = EXP2F(sa[kt][0]), p1 = EXP2F(sa[kt][1]);
        const float p2 = EXP2F(sa[kt][2]), p3 = EXP2F(sa[kt][3]);
        l_part += (p0 + p1) + (p2 + p3);
        uint2 pk; pk.x = pack2bf(p0, p1); pk.y = pack2bf(p2, p3);
        *(uint2*)pdst = pk;
      } else if ((kt >> 1) * 32 <= krel) {      // zero-fill rest of read half
        uint2 z; z.x = 0u; z.y = 0u;
        *(uint2*)pdst = z;
      }
    }
    asm volatile("s_waitcnt lgkmcnt(0)" ::: "memory");  // P writes (wave-local)

    // O^T += V^T P^T : A = Vt frag (swizzled LDS), B = P frag (b64 reads)
#pragma unroll
    for (int ks = 0; ks < 2; ks++) {
      if (ks * 32 > krel) break;
      const unsigned short* ps = &Pw[l15 * 68 + ks * 32 + quad * 8];
      union { ushort4v h[2]; bf16x8 v; } pu;
      pu.h[0] = *(const ushort4v*)ps;
      pu.h[1] = *(const ushort4v*)(ps + 4);
      __builtin_amdgcn_s_setprio(1);            // T5: favor MFMA wave (m191)
#pragma unroll
      for (int mt = 0; mt < 4; mt++) {
        const bf16x8 vf = *(const bf16x8*)(&Vsb[(mt * 16 + l15) * 64] + (ks ? sw1 : sw0));
        O[mt] = __builtin_amdgcn_mfma_f32_16x16x32_bf16(vf, pu.v, O[mt], 0, 0, 0);
      }
      __builtin_amdgcn_s_setprio(0);
    }
  }

  // l: reduce partial sums across the 4 quads (keys were split across quads)
#pragma unroll
  for (int d = 16; d < 64; d <<= 1)
    l_part += __shfl_xor(l_part, d, 64);

  // epilogue: O^T (hd=row, q=col) -> Pw [q][hd] stride 68 -> coalesced CTX
  {
    const float inv = 1.0f / l_part;
#pragma unroll
    for (int mt = 0; mt < 4; mt++)
#pragma unroll
      for (int a = 0; a < 2; a++) {
        const unsigned int pk =
            (unsigned int)f2bf(O[mt][2 * a] * inv) |
            ((unsigned int)f2bf(O[mt][2 * a + 1] * inv) << 16);
        *(unsigned int*)&Pw[l15 * 68 + mt * 16 + quad * 4 + 2 * a] = pk;
      }
  }
  asm volatile("s_waitcnt lgkmcnt(0)" ::: "memory");
  const int b = bh >> 4, h = bh & 15;
#pragma unroll
  for (int it = 0; it < 2; it++) {
    const int g = it * 64 + lane;
    const int row = g >> 3, c8 = (g & 7) * 8;
    union { ushort4v h[2]; ushort8v v; } ou;
    ou.h[0] = *(const ushort4v*)&Pw[row * 68 + c8];
    ou.h[1] = *(const ushort4v*)&Pw[row * 68 + c8 + 4];
    const int s = qw + row;
    *(ushort8v*)&CTX[((size_t)(b * S_LEN + s)) * KD + h * HDIM + c8] = ou.v;
  }
}

// ---------------------------------------------------------------------------
// Kernel 4: output projection ctx[8192,1024] x W_o[1024,1024]^T + b_o -> fp32
// R13: R11 K-loop (both operands LDS-staged) with SWAP mfma -> n-major acc ->
// coalesced float4 stores + vector bias (epilogue validated in R12).
// ---------------------------------------------------------------------------
__global__ __launch_bounds__(256) void gemm_out(
    const unsigned short* __restrict__ A,
    const unsigned short* __restrict__ Bw,
    const float* __restrict__ bias,
    float* __restrict__ out)
{
  __shared__ unsigned short smem[16384];   // buf0 As|Bs, buf1 As|Bs
  const int tid  = threadIdx.x;
  const int wave = tid >> 6, lane = tid & 63;
  const int quad = lane >> 4, l15 = lane & 15;
  const int wr = wave >> 1, wc = wave & 1;
  const int m0 = blockIdx.x * 128, n0 = blockIdx.y * 128;

  const int srow = lane >> 2;
  const int scol = ((lane & 3) ^ ((srow >> 1) & 3)) * 8;
  const unsigned short* gA = A  + (size_t)(m0 + wave * 32 + srow) * KD + scol;
  const unsigned short* gB = Bw + (size_t)(n0 + wave * 32 + srow) * KD + scol;

  const floatx4 fzero = {0.f, 0.f, 0.f, 0.f};
  floatx4 acc[4][4];
#pragma unroll
  for (int i = 0; i < 4; i++)
#pragma unroll
    for (int j = 0; j < 4; j++) acc[i][j] = fzero;

  kloop128<true>(gA, gB, smem, acc, wave, quad, l15, wr, wc);

  // swapped acc: acc[i][j][r] = C[m=m0+wr*64+i*16+l15][n=n0+wc*64+j*16+quad*4+r]
#pragma unroll
  for (int j = 0; j < 4; j++) {
    const int nb4 = n0 + wc * 64 + j * 16 + quad * 4;
    const float4v bb = *(const float4v*)&bias[nb4];
#pragma unroll
    for (int i = 0; i < 4; i++) {
      const int m = m0 + wr * 64 + i * 16 + l15;
      float4v st;
#pragma unroll
      for (int r = 0; r < 4; r++) st[r] = acc[i][j][r] + bb[r];
      *(float4v*)&out[(size_t)m * KD + nb4] = st;
    }
  }
}

// ---------------------------------------------------------------------------
extern "C" void kernel_launch(void* const* d_in, const int* in_sizes, int n_in,
                              void* d_out, int out_size, void* d_ws, size_t ws_size,
                              hipStream_t stream) {
  (void)in_sizes; (void)n_in; (void)out_size;
  const float* x  = (const float*)d_in[0];
  const float* wq = (const float*)d_in[1];
  const float* wk = (const float*)d_in[2];
  const float* wv = (const float*)d_in[3];
  const float* wo = (const float*)d_in[4];
  const float* bo = (const float*)d_in[5];
  float* out = (float*)d_out;

  if (ws_size < (size_t)92274688) return;
  char* ws = (char*)d_ws;
  unsigned short* xb    = (unsigned short*)(ws);
  unsigned short* wqkvb = (unsigned short*)(ws + (size_t)16777216);
  unsigned short* wob   = (unsigned short*)(ws + (size_t)23068672);
  unsigned short* qws   = (unsigned short*)(ws + (size_t)25165824);
  unsigned short* kws   = (unsigned short*)(ws + (size_t)41943040);
  unsigned short* vtws  = (unsigned short*)(ws + (size_t)58720256);
  unsigned short* ctxws = (unsigned short*)(ws + (size_t)75497472);

  cvt_kernel<<<12288, 256, 0, stream>>>(x, wq, wk, wv, wo, xb, wqkvb, wob);
  gemm_qkv<<<dim3(64, 24), 256, 0, stream>>>(xb, wqkvb, qws, kws, vtws);
  attn_kernel<<<dim3(64, 16), 512, 0, stream>>>(qws, kws, vtws, ctxws);
  gemm_out<<<dim3(64, 8), 256, 0, stream>>>(ctxws, wob, bo, out);
}

// Round 7
// 230.316 us; speedup vs baseline: 1.3324x; 1.0528x over previous
//
#include <hip/hip_runtime.h>
#include <cstdint>
#include <cstddef>

// Problem constants
#define S_LEN  2048
#define NHEAD  16
#define HDIM   64
#define KD     1024   // D_IN == D_OUT
#define BSROWS 8192   // B * S

typedef __attribute__((ext_vector_type(4))) float          floatx4;
typedef __attribute__((ext_vector_type(8))) __bf16         bf16x8;
typedef __attribute__((ext_vector_type(8))) unsigned short ushort8v;
typedef __attribute__((ext_vector_type(4))) unsigned short ushort4v;
typedef __attribute__((ext_vector_type(4))) float          float4v;

// fp32 -> bf16 round-to-nearest-even on the bit pattern (inputs are finite)
__device__ __forceinline__ unsigned short f2bf(float f) {
  unsigned int u = __float_as_uint(f);
  u += 0x7fffu + ((u >> 16) & 1u);
  return (unsigned short)(u >> 16);
}

// fast exp2 (single v_exp_f32)
#if __has_builtin(__builtin_amdgcn_exp2f)
#define EXP2F(x) __builtin_amdgcn_exp2f(x)
#else
#define EXP2F(x) exp2f(x)
#endif

// pack two fp32 into packed bf16 (truncation; bias cancels in O/l)
__device__ __forceinline__ unsigned int pack2bf(float a, float b) {
#if __has_builtin(__builtin_amdgcn_perm)
  return __builtin_amdgcn_perm(__float_as_uint(b), __float_as_uint(a), 0x07060302);
#else
  return (__float_as_uint(a) >> 16) | (__float_as_uint(b) & 0xffff0000u);
#endif
}

// async global->LDS, 16B per lane; LDS dest is wave-uniform base + lane*16
__device__ __forceinline__ void async_cp16(const void* gsrc, void* ldst) {
  __builtin_amdgcn_global_load_lds(
      (__attribute__((address_space(1))) void*)gsrc,
      (__attribute__((address_space(3))) void*)ldst,
      16, 0, 0);
}

// ---------------------------------------------------------------------------
// Kernel 1: fp32 -> bf16 conversion of x, W_q|W_k|W_v (concat), W_o
// ---------------------------------------------------------------------------
#define XN4 2097152   // B*S*D_IN / 4
#define WN4 262144    // 1024*1024 / 4

__global__ __launch_bounds__(256) void cvt_kernel(
    const float* __restrict__ x,  const float* __restrict__ wq,
    const float* __restrict__ wk, const float* __restrict__ wv,
    const float* __restrict__ wo,
    unsigned short* __restrict__ xb, unsigned short* __restrict__ wqkvb,
    unsigned short* __restrict__ wob)
{
  const int i = blockIdx.x * 256 + threadIdx.x;
  const float* src; unsigned short* dst; int off;
  if (i < XN4) { src = x; dst = xb; off = i; }
  else {
    const int j = i - XN4;
    if (j < WN4)          { src = wq; dst = wqkvb;           off = j; }
    else if (j < 2*WN4)   { src = wk; dst = wqkvb + 4*WN4;   off = j - WN4; }
    else if (j < 3*WN4)   { src = wv; dst = wqkvb + 8*WN4;   off = j - 2*WN4; }
    else                  { src = wo; dst = wob;             off = j - 3*WN4; }
  }
  const float4v v = ((const float4v*)src)[off];
  ushort4v o;
  o.x = f2bf(v.x); o.y = f2bf(v.y); o.z = f2bf(v.z); o.w = f2bf(v.w);
  ((ushort4v*)dst)[off] = o;
}

// ---------------------------------------------------------------------------
// R14: 256x256 8-phase counted-vmcnt GEMM for the QKV projection (T2+T3+T4+T5).
//
// Geometry: BM=BN=256, BK=64, 512 thr = 8 waves (2 row-bands x 4 col-bands per
// 128x128 quadrant). LDS = 2 K-tile buffers x (A[256][64] + B[256][64]) bf16
// = 128 KiB. K = 1024 -> 16 K-tiles x 4 quadrant-phases.
//
// Schedule (derived; every hazard checked):
//  - half-tile order per tile: pos 0:A0(rows0-127) 1:B0 2:B1(rows128-255) 3:A1
//  - phase (t,q) stages half-tile j = 4t+q+6  (6-half-tile issue lead)
//      q0 -> B1(t+1), q1 -> A1(t+1)  [other buffer, never conflicts]
//      q2 -> A0(t+2), q3 -> B0(t+2)  [this buffer; those regions were last
//        READ >=2 phase-barriers earlier: A0 read only in q0, B0 only in q0
//        (B0 regs are held and reused at q2) -> write-after-read safe]
//  - ONE counted wait per K-tile at q0 (after its stage): issued-through =
//    4t+6 halves, need tile-t prefix 4t+3 -> outstanding <= 3 half-tiles
//    = s_waitcnt vmcnt(6); last tile uses vmcnt(0). Loads never drain to 0
//    in steady state (T4).
//  - per-phase: open barrier; stage issue; [q0: vmcnt+barrier]; ds_read
//    (q0: A-half+B-half=12 b128, q1: 4, q2: 8, q3: 0 — B halves live in regs
//    across the tile); setprio(1); 16 MFMA; setprio(0).
//  - swizzle: global-source XOR chunk (tid&7)^(row&7), LDS linear dest,
//    read at chunk (ks*4+quad)^(l15&7) — the exact pattern HW-verified by
//    this session's attn kernel staging/reads.
// ---------------------------------------------------------------------------
__device__ __forceinline__ void stage_j(
    int j, const unsigned short* __restrict__ gAs,
    const unsigned short* __restrict__ gBs,
    unsigned short* smem, const int wave)
{
  const int tk  = j >> 2, pos = j & 3;
  const int bufo = (tk & 1) << 15;                 // *32768 shorts
  const bool isA = (pos == 0) | (pos == 3);
  const int rowbase = (pos >= 2) ? 128 : 0;
  const unsigned short* g = (isA ? gAs : gBs) + (size_t)rowbase * KD + tk * 64;
  unsigned short* l = smem + bufo + (isA ? 0 : 16384) + rowbase * 64 + wave * 512;
  async_cp16(g,                  l);
  async_cp16(g + (size_t)64 * KD, l + 4096);
}

template<bool SWAP>
__device__ __forceinline__ void kloop256(
    const unsigned short* __restrict__ gAs,
    const unsigned short* __restrict__ gBs,
    unsigned short* smem, floatx4 (&acc)[8][4],
    const int wave, const int quad, const int l15)
{
  const int ar_base = (wave >> 2) * 64 + l15;     // wave row-band + lane row
  const int br_base = (wave & 3) * 32 + l15;      // wave col-band + lane row
  const int sw0 = ((quad)     ^ (l15 & 7)) * 8;   // chunk swizzle, ks=0
  const int sw1 = ((4 + quad) ^ (l15 & 7)) * 8;   // chunk swizzle, ks=1

  bf16x8 af[4][2];        // A frags of current m-half (reloaded q0/q2)
  bf16x8 bfr[2][2][2];    // BOTH B halves, held across the tile

  // prologue: tile0 complete + A0,B0 of tile1  (j = 0..5)
#pragma unroll
  for (int j = 0; j < 6; ++j) stage_j(j, gAs, gBs, smem, wave);

#define LOADA(mh)                                                              \
  _Pragma("unroll") for (int mt = 0; mt < 4; ++mt) {                           \
    const unsigned short* ar = &As[((mh) * 128 + ar_base + mt * 16) * 64];     \
    af[mt][0] = *(const bf16x8*)(ar + sw0);                                    \
    af[mt][1] = *(const bf16x8*)(ar + sw1);                                    \
  }
#define LOADB(nh)                                                              \
  _Pragma("unroll") for (int nt = 0; nt < 2; ++nt) {                           \
    const unsigned short* br = &Bs[((nh) * 128 + br_base + nt * 16) * 64];     \
    bfr[nh][nt][0] = *(const bf16x8*)(br + sw0);                               \
    bfr[nh][nt][1] = *(const bf16x8*)(br + sw1);                               \
  }
#define MFMAQ(mh, nh)                                                          \
  __builtin_amdgcn_s_setprio(1);                                               \
  _Pragma("unroll") for (int mt = 0; mt < 4; ++mt)                             \
    _Pragma("unroll") for (int nt = 0; nt < 2; ++nt)                           \
      _Pragma("unroll") for (int ks = 0; ks < 2; ++ks) {                       \
        if (SWAP)                                                              \
          acc[(mh)*4+mt][(nh)*2+nt] = __builtin_amdgcn_mfma_f32_16x16x32_bf16( \
              bfr[nh][nt][ks], af[mt][ks], acc[(mh)*4+mt][(nh)*2+nt], 0,0,0);  \
        else                                                                   \
          acc[(mh)*4+mt][(nh)*2+nt] = __builtin_amdgcn_mfma_f32_16x16x32_bf16( \
              af[mt][ks], bfr[nh][nt][ks], acc[(mh)*4+mt][(nh)*2+nt], 0,0,0);  \
      }                                                                        \
  __builtin_amdgcn_s_setprio(0);

#pragma unroll 2
  for (int t = 0; t < 16; ++t) {
    const unsigned short* As = smem + ((t & 1) << 15);
    const unsigned short* Bs = As + 16384;
    const int j0 = 4 * t + 6;

    // ---- q0: quadrant (mh0, nh0)
    asm volatile("s_barrier" ::: "memory");          // close prev phase
    if (j0 < 64) stage_j(j0, gAs, gBs, smem, wave);  // B1(t+1)
    if (t < 15) asm volatile("s_waitcnt vmcnt(6)\n\ts_barrier" ::: "memory");
    else        asm volatile("s_waitcnt vmcnt(0)\n\ts_barrier" ::: "memory");
    LOADA(0)
    LOADB(0)
    MFMAQ(0, 0)

    // ---- q1: (mh0, nh1)
    asm volatile("s_barrier" ::: "memory");
    if (j0 + 1 < 64) stage_j(j0 + 1, gAs, gBs, smem, wave);  // A1(t+1)
    LOADB(1)
    MFMAQ(0, 1)

    // ---- q2: (mh1, nh0)  (B0 reused from regs)
    asm volatile("s_barrier" ::: "memory");
    if (j0 + 2 < 64) stage_j(j0 + 2, gAs, gBs, smem, wave);  // A0(t+2)
    LOADA(1)
    MFMAQ(1, 0)

    // ---- q3: (mh1, nh1)  (no ds_reads)
    asm volatile("s_barrier" ::: "memory");
    if (j0 + 3 < 64) stage_j(j0 + 3, gAs, gBs, smem, wave);  // B0(t+2)
    MFMAQ(1, 1)
  }
#undef LOADA
#undef LOADB
#undef MFMAQ
}

// fragment coords (SWAP, n-major):   m = mh*128+(w>>2)*64+mt*16+l15,
//                                    n = (jn>>1)*128+(w&3)*32+(jn&1)*16+quad*4+r
// (no-SWAP, m-major): m gets quad*4+r, n gets l15.
__global__ __launch_bounds__(512, 2) void gemm_qkv8(
    const unsigned short* __restrict__ A,
    const unsigned short* __restrict__ Bw,
    unsigned short* __restrict__ Qo,
    unsigned short* __restrict__ Ko,
    unsigned short* __restrict__ Vto)
{
  __shared__ unsigned short smem[65536];   // 128 KiB
  const int tid  = threadIdx.x;
  const int wave = tid >> 6, lane = tid & 63;
  const int quad = lane >> 4, l15 = lane & 15;

  // XCD swizzle (384 = 8 x 48, bijective); m-major within XCD: 6 A-panels
  // (3 MB) stay L2-resident per XCD, B streams from L3.
  const int bid = (int)blockIdx.x;
  const int tau = (bid & 7) * 48 + (bid >> 3);
  const int m0 = (tau / 12) * 256, n0 = (tau % 12) * 256;

  const int strow = tid >> 3;                       // 0..63
  const int stxc  = (tid & 7) ^ (strow & 7);        // XOR-swizzled source chunk
  const unsigned short* gAs = A  + (size_t)(m0 + strow) * KD + stxc * 8;
  const unsigned short* gBs = Bw + (size_t)(n0 + strow) * KD + stxc * 8;

  const floatx4 fzero = {0.f, 0.f, 0.f, 0.f};
  floatx4 acc[8][4];
#pragma unroll
  for (int i = 0; i < 8; i++)
#pragma unroll
    for (int j = 0; j < 4; j++) acc[i][j] = fzero;

  const int which = n0 >> 10;                       // 0:Q 1:K 2:V
  if (which < 2) kloop256<true >(gAs, gBs, smem, acc, wave, quad, l15);
  else           kloop256<false>(gAs, gBs, smem, acc, wave, quad, l15);

  const int h0 = (n0 & 1023) >> 6;                  // first of 4 heads
  const int b = m0 >> 11, sl = m0 & 2047;
  __syncthreads();                                  // staging dead -> reuse LDS

  if (which < 2) {
    unsigned short* dst = which ? Ko : Qo;
    const float scale = which ? 1.0f : 0.18033688011112042f;  // Q: 0.125*log2(e)
#pragma unroll
    for (int mh = 0; mh < 2; ++mh) {               // two 128-row halves
      if (mh) __syncthreads();
      // stage Ct[s 128][n 256] stride 264 (2-way bank alias only)
#pragma unroll
      for (int mt = 0; mt < 4; ++mt)
#pragma unroll
        for (int jn = 0; jn < 4; ++jn) {
          ushort4v t4;
#pragma unroll
          for (int r = 0; r < 4; ++r) t4[r] = f2bf(acc[mh * 4 + mt][jn][r] * scale);
          const int row = (wave >> 2) * 64 + mt * 16 + l15;
          const int col = (jn >> 1) * 128 + (wave & 3) * 32 + (jn & 1) * 16 + quad * 4;
          *(ushort4v*)&smem[row * 264 + col] = t4;
        }
      __syncthreads();
#pragma unroll
      for (int t8 = 0; t8 < 8; ++t8) {
        const int c = t8 * 512 + tid;
        const int sr = c >> 5, ch = c & 31;
        const int hs = ch >> 3, hd8 = (ch & 7) * 8;
        const ushort8v val = *(const ushort8v*)&smem[sr * 264 + hs * 64 + hd8];
        *(ushort8v*)&dst[((size_t)((b * NHEAD + h0 + hs) * S_LEN + sl + mh * 128 + sr)) * HDIM + hd8] = val;
      }
    }
  } else {
    // V: stage TRANSPOSED Ct[n 256][s 128] stride 136, store Vt[b,h,hd,s]
#pragma unroll
    for (int mh = 0; mh < 2; ++mh) {
      if (mh) __syncthreads();
#pragma unroll
      for (int mt = 0; mt < 4; ++mt)
#pragma unroll
        for (int jn = 0; jn < 4; ++jn) {
          ushort4v t4;
#pragma unroll
          for (int r = 0; r < 4; ++r) t4[r] = f2bf(acc[mh * 4 + mt][jn][r]);
          const int nl = (jn >> 1) * 128 + (wave & 3) * 32 + (jn & 1) * 16 + l15;
          const int sc = (wave >> 2) * 64 + mt * 16 + quad * 4;
          *(ushort4v*)&smem[nl * 136 + sc] = t4;
        }
      __syncthreads();
#pragma unroll
      for (int t8 = 0; t8 < 8; ++t8) {
        const int c = t8 * 512 + tid;
        const int nl = c >> 4, sc = (c & 15) * 8;
        const ushort8v val = *(const ushort8v*)&smem[nl * 136 + sc];
        *(ushort8v*)&Vto[((size_t)((b * NHEAD + h0 + (nl >> 6)) * HDIM + (nl & 63))) * S_LEN + sl + mh * 128 + sc] = val;
      }
    }
  }
}

// ---------------------------------------------------------------------------
// Shared 128x128 K-loop (R11-verified structure) — still used by gemm_out.
// ---------------------------------------------------------------------------
template<bool SWAP>
__device__ __forceinline__ void kloop128(
    const unsigned short* __restrict__ gA,
    const unsigned short* __restrict__ gB,
    unsigned short* smem, floatx4 (&acc)[4][4],
    const int wave, const int quad, const int l15,
    const int wr, const int wc)
{
  {
    unsigned short* lA = smem + wave * 1024;
    unsigned short* lB = smem + 4096 + wave * 1024;
    async_cp16(gA,                    lA);
    async_cp16(gA + (size_t)16 * KD,  lA + 512);
    async_cp16(gB,                    lB);
    async_cp16(gB + (size_t)16 * KD,  lB + 512);
  }
  const int lsw = (l15 >> 1) & 3;

#pragma unroll 2
  for (int it = 0; it < 32; it++) {
    asm volatile("s_waitcnt vmcnt(0) lgkmcnt(0)\n\ts_barrier" ::: "memory");
    if (it + 1 < 32) {
      const int nb = (it + 1) & 1;
      const int ko = (it + 1) * 32;
      unsigned short* lA = smem + nb * 8192 + wave * 1024;
      unsigned short* lB = smem + nb * 8192 + 4096 + wave * 1024;
      async_cp16(gA + ko,                   lA);
      async_cp16(gA + ko + (size_t)16 * KD, lA + 512);
      async_cp16(gB + ko,                   lB);
      async_cp16(gB + ko + (size_t)16 * KD, lB + 512);
    }
    const unsigned short* As = smem + (it & 1) * 8192;
    const unsigned short* Bs = As + 4096;

    bf16x8 af[4], bfrag[4];
#pragma unroll
    for (int i = 0; i < 4; i++)
      af[i] = *(const bf16x8*)&As[(wr * 64 + i * 16 + l15) * 32 + (quad ^ lsw) * 8];
#pragma unroll
    for (int j = 0; j < 4; j++)
      bfrag[j] = *(const bf16x8*)&Bs[(wc * 64 + j * 16 + l15) * 32 + (quad ^ lsw) * 8];
#pragma unroll
    for (int i = 0; i < 4; i++)
#pragma unroll
      for (int j = 0; j < 4; j++) {
        if (SWAP)
          acc[i][j] = __builtin_amdgcn_mfma_f32_16x16x32_bf16(bfrag[j], af[i], acc[i][j], 0, 0, 0);
        else
          acc[i][j] = __builtin_amdgcn_mfma_f32_16x16x32_bf16(af[i], bfrag[j], acc[i][j], 0, 0, 0);
      }
  }
}

// ---------------------------------------------------------------------------
// Kernel 3: causal flash attention, S^T formulation, ASYNC-PIPELINED.
// (unchanged — verified in the 239.2/242.5 µs runs)
// ---------------------------------------------------------------------------
__global__ __launch_bounds__(512, 6) void attn_kernel(
    const unsigned short* __restrict__ Qg_,
    const unsigned short* __restrict__ Kg_,
    const unsigned short* __restrict__ Vtg_,
    unsigned short* __restrict__ CTX)
{
  // shorts: buf0 K@0[4096] V@4096[4096] | buf1 K@8192 V@12288 | P@16384 8x[16*68]
  __shared__ unsigned short smem[25088];   // 50176 B
  const int tid  = threadIdx.x, wave = tid >> 6, lane = tid & 63;
  const int quad = lane >> 4, l15 = lane & 15;
  unsigned short* Pw = smem + 16384 + wave * 1088;   // [16][68] per wave

  const int bh = (int)blockIdx.x;
  const int yy = (int)blockIdx.y;
  // qt perm: {0,1,2,3, 7,6,5,4, 8,9,10,11, 15,14,13,12} — columns sum to 30
  const int qt = (yy < 4) ? yy : (yy < 8) ? (11 - yy) : (yy < 12) ? yy : (27 - yy);
  const int q0 = qt * 128;
  const size_t base = (size_t)bh * (S_LEN * HDIM);
  const unsigned short* Qg  = Qg_  + base;
  const unsigned short* Kg  = Kg_  + base;
  const unsigned short* Vtg = Vtg_ + base;        // [hd][s]
  const int qw = q0 + wave * 16;                  // wave's 16 q-rows

  const int strow = lane >> 3;
  const int stxc  = (lane & 7) ^ strow;
  const unsigned short* kstage = Kg  + (size_t)(wave * 8 + strow) * HDIM  + stxc * 8;
  const unsigned short* vstage = Vtg + (size_t)(wave * 8 + strow) * S_LEN + stxc * 8;
  unsigned short* kd0 = smem + wave * 512;
  unsigned short* vd0 = smem + 4096 + wave * 512;

  // prologue: async stage tile 0 -> buf 0
  async_cp16(kstage, kd0);
  async_cp16(vstage, vd0);

  // Q fragments direct from global (one-time; B-operand B[n=q][k=dim])
  bf16x8 qf[2];
#pragma unroll
  for (int ks = 0; ks < 2; ks++)
    qf[ks] = *(const bf16x8*)&Qg[(size_t)(qw + l15) * HDIM + ks * 32 + quad * 8];

  const int sw0 = ((quad)     ^ (l15 & 7)) * 8;   // K/V frag swizzled col offs
  const int sw1 = ((4 + quad) ^ (l15 & 7)) * 8;

  const floatx4 fzero = {0.f, 0.f, 0.f, 0.f};
  floatx4 O[4];
  float l_part = 0.f;
#pragma unroll
  for (int mt = 0; mt < 4; mt++) O[mt] = fzero;

  const int ntiles = 2 * qt + 2;   // covers keys 0..q0+127 >= qw+15

  for (int j = 0; j < ntiles; j++) {
    asm volatile("s_waitcnt vmcnt(0) lgkmcnt(0)\n\ts_barrier" ::: "memory");
    if (j + 1 < ntiles) {
      const int nb = (j + 1) & 1;
      async_cp16(kstage + (size_t)(j + 1) * 64 * HDIM, kd0 + nb * 8192);
      async_cp16(vstage + (size_t)(j + 1) * 64,        vd0 + nb * 8192);
    }
    const int k0 = j * 64;
    if (k0 > qw + 15) continue;                 // above diagonal for this wave
    const unsigned short* Ksb = smem + (j & 1) * 8192;
    const unsigned short* Vsb = Ksb + 4096;
    const int krel = qw + 15 - k0;              // max key offset needed

    // S^T = K Q^T  (A = K frag just-in-time, B = Q reg frag)
    floatx4 sa[4];
#pragma unroll
    for (int kt = 0; kt < 4; kt++) sa[kt] = fzero;
    __builtin_amdgcn_s_setprio(1);              // T5: favor MFMA wave (m191)
#pragma unroll
    for (int kt = 0; kt < 4; kt++) {
      if (kt * 16 <= krel) {
        const unsigned short* kr = &Ksb[(kt * 16 + l15) * 64];
        sa[kt] = __builtin_amdgcn_mfma_f32_16x16x32_bf16(*(const bf16x8*)(kr + sw0), qf[0], sa[kt], 0, 0, 0);
        sa[kt] = __builtin_amdgcn_mfma_f32_16x16x32_bf16(*(const bf16x8*)(kr + sw1), qf[1], sa[kt], 0, 0, 0);
      }
    }
    __builtin_amdgcn_s_setprio(0);

    const int qrow = qw + l15;                  // this lane's q (S^T col)
#pragma unroll
    for (int kt = 0; kt < 4; kt++) {
      const int kbase = k0 + kt * 16;
      unsigned short* pdst = &Pw[l15 * 68 + kt * 16 + quad * 4];
      if (kt * 16 <= krel) {
        if (kbase + 15 > qw) {                  // boundary subtile: mask
#pragma unroll
          for (int r = 0; r < 4; r++)
            if (kbase + quad * 4 + r > qrow) sa[kt][r] = -INFINITY;
        }
        const float p0 = EXP2F(sa[kt][0]), p1 = EXP2F(sa[kt][1]);
        const float p2 = EXP2F(sa[kt][2]), p3 = EXP2F(sa[kt][3]);
        l_part += (p0 + p1) + (p2 + p3);
        uint2 pk; pk.x = pack2bf(p0, p1); pk.y = pack2bf(p2, p3);
        *(uint2*)pdst = pk;
      } else if ((kt >> 1) * 32 <= krel) {      // zero-fill rest of read half
        uint2 z; z.x = 0u; z.y = 0u;
        *(uint2*)pdst = z;
      }
    }
    asm volatile("s_waitcnt lgkmcnt(0)" ::: "memory");  // P writes (wave-local)

    // O^T += V^T P^T : A = Vt frag (swizzled LDS), B = P frag (b64 reads)
#pragma unroll
    for (int ks = 0; ks < 2; ks++) {
      if (ks * 32 > krel) break;
      const unsigned short* ps = &Pw[l15 * 68 + ks * 32 + quad * 8];
      union { ushort4v h[2]; bf16x8 v; } pu;
      pu.h[0] = *(const ushort4v*)ps;
      pu.h[1] = *(const ushort4v*)(ps + 4);
      __builtin_amdgcn_s_setprio(1);            // T5: favor MFMA wave (m191)
#pragma unroll
      for (int mt = 0; mt < 4; mt++) {
        const bf16x8 vf = *(const bf16x8*)(&Vsb[(mt * 16 + l15) * 64] + (ks ? sw1 : sw0));
        O[mt] = __builtin_amdgcn_mfma_f32_16x16x32_bf16(vf, pu.v, O[mt], 0, 0, 0);
      }
      __builtin_amdgcn_s_setprio(0);
    }
  }

  // l: reduce partial sums across the 4 quads (keys were split across quads)
#pragma unroll
  for (int d = 16; d < 64; d <<= 1)
    l_part += __shfl_xor(l_part, d, 64);

  // epilogue: O^T (hd=row, q=col) -> Pw [q][hd] stride 68 -> coalesced CTX
  {
    const float inv = 1.0f / l_part;
#pragma unroll
    for (int mt = 0; mt < 4; mt++)
#pragma unroll
      for (int a = 0; a < 2; a++) {
        const unsigned int pk =
            (unsigned int)f2bf(O[mt][2 * a] * inv) |
            ((unsigned int)f2bf(O[mt][2 * a + 1] * inv) << 16);
        *(unsigned int*)&Pw[l15 * 68 + mt * 16 + quad * 4 + 2 * a] = pk;
      }
  }
  asm volatile("s_waitcnt lgkmcnt(0)" ::: "memory");
  const int b = bh >> 4, h = bh & 15;
#pragma unroll
  for (int it = 0; it < 2; it++) {
    const int g = it * 64 + lane;
    const int row = g >> 3, c8 = (g & 7) * 8;
    union { ushort4v h[2]; ushort8v v; } ou;
    ou.h[0] = *(const ushort4v*)&Pw[row * 68 + c8];
    ou.h[1] = *(const ushort4v*)&Pw[row * 68 + c8 + 4];
    const int s = qw + row;
    *(ushort8v*)&CTX[((size_t)(b * S_LEN + s)) * KD + h * HDIM + c8] = ou.v;
  }
}

// ---------------------------------------------------------------------------
// Kernel 4: output projection ctx[8192,1024] x W_o[1024,1024]^T + b_o -> fp32
// (unchanged from R13: kloop128<true> + coalesced float4 stores)
// ---------------------------------------------------------------------------
__global__ __launch_bounds__(256) void gemm_out(
    const unsigned short* __restrict__ A,
    const unsigned short* __restrict__ Bw,
    const float* __restrict__ bias,
    float* __restrict__ out)
{
  __shared__ unsigned short smem[16384];   // buf0 As|Bs, buf1 As|Bs
  const int tid  = threadIdx.x;
  const int wave = tid >> 6, lane = tid & 63;
  const int quad = lane >> 4, l15 = lane & 15;
  const int wr = wave >> 1, wc = wave & 1;
  const int m0 = blockIdx.x * 128, n0 = blockIdx.y * 128;

  const int srow = lane >> 2;
  const int scol = ((lane & 3) ^ ((srow >> 1) & 3)) * 8;
  const unsigned short* gA = A  + (size_t)(m0 + wave * 32 + srow) * KD + scol;
  const unsigned short* gB = Bw + (size_t)(n0 + wave * 32 + srow) * KD + scol;

  const floatx4 fzero = {0.f, 0.f, 0.f, 0.f};
  floatx4 acc[4][4];
#pragma unroll
  for (int i = 0; i < 4; i++)
#pragma unroll
    for (int j = 0; j < 4; j++) acc[i][j] = fzero;

  kloop128<true>(gA, gB, smem, acc, wave, quad, l15, wr, wc);

  // swapped acc: acc[i][j][r] = C[m=m0+wr*64+i*16+l15][n=n0+wc*64+j*16+quad*4+r]
#pragma unroll
  for (int j = 0; j < 4; j++) {
    const int nb4 = n0 + wc * 64 + j * 16 + quad * 4;
    const float4v bb = *(const float4v*)&bias[nb4];
#pragma unroll
    for (int i = 0; i < 4; i++) {
      const int m = m0 + wr * 64 + i * 16 + l15;
      float4v st;
#pragma unroll
      for (int r = 0; r < 4; r++) st[r] = acc[i][j][r] + bb[r];
      *(float4v*)&out[(size_t)m * KD + nb4] = st;
    }
  }
}

// ---------------------------------------------------------------------------
extern "C" void kernel_launch(void* const* d_in, const int* in_sizes, int n_in,
                              void* d_out, int out_size, void* d_ws, size_t ws_size,
                              hipStream_t stream) {
  (void)in_sizes; (void)n_in; (void)out_size;
  const float* x  = (const float*)d_in[0];
  const float* wq = (const float*)d_in[1];
  const float* wk = (const float*)d_in[2];
  const float* wv = (const float*)d_in[3];
  const float* wo = (const float*)d_in[4];
  const float* bo = (const float*)d_in[5];
  float* out = (float*)d_out;

  if (ws_size < (size_t)92274688) return;
  char* ws = (char*)d_ws;
  unsigned short* xb    = (unsigned short*)(ws);
  unsigned short* wqkvb = (unsigned short*)(ws + (size_t)16777216);
  unsigned short* wob   = (unsigned short*)(ws + (size_t)23068672);
  unsigned short* qws   = (unsigned short*)(ws + (size_t)25165824);
  unsigned short* kws   = (unsigned short*)(ws + (size_t)41943040);
  unsigned short* vtws  = (unsigned short*)(ws + (size_t)58720256);
  unsigned short* ctxws = (unsigned short*)(ws + (size_t)75497472);

  cvt_kernel<<<12288, 256, 0, stream>>>(x, wq, wk, wv, wo, xb, wqkvb, wob);
  gemm_qkv8<<<384, 512, 0, stream>>>(xb, wqkvb, qws, kws, vtws);
  attn_kernel<<<dim3(64, 16), 512, 0, stream>>>(qws, kws, vtws, ctxws);
  gemm_out<<<dim3(64, 8), 256, 0, stream>>>(ctxws, wob, bo, out);
}